// Round 1
// baseline (232.788 us; speedup 1.0000x reference)
//
#include <hip/hip_runtime.h>

// AttributeDecoder: gather K*S rows (D=256) from features (N,256), per-head
// Linear 256->8 + bias. fp32.
// R3: VALU-cut round at identical memory behavior.
//  - W columns loaded per-lane XOR-permuted (w[t][j] = W[d][j^ (lane&7)]):
//    the v-space split-butterfly needs NO cndmask routing (28 -> 14 ops/s).
//  - tail rounds xor8/xor16 split over the s dimension (lane bits 3,4),
//    xor32 plain: 27 -> 14 ops per 4 s, store mapping unchanged.
//  - gather addresses scalarized: readfirstlane(row) -> s_lshl/s_add base,
//    global_load_dwordx4 saddr + constant lane*16 voffset (addr math on SALU).
//  - next mask_idx int4 prefetched one group ahead.

#define KH 24
#define SS 16384
#define VV 8
#define DD 256

template <int CTRL>
__device__ __forceinline__ float dpp_mov(float x) {
    int xi = __builtin_bit_cast(int, x);
    int r = __builtin_amdgcn_update_dpp(xi, xi, CTRL, 0xF, 0xF, false);
    return __builtin_bit_cast(float, r);
}

__global__ __launch_bounds__(256) void attr_decoder_kernel(
    const float* __restrict__ feats,      // (131072, 256)
    const int*   __restrict__ mask_idx,   // (24, 16384)
    const float* __restrict__ head_w,     // (24, 256, 8)
    const float* __restrict__ head_b,     // (24, 8)
    float*       __restrict__ out)        // (24, 16384, 8)
{
    const int lane  = threadIdx.x & 63;
    const int wv    = __builtin_amdgcn_readfirstlane(threadIdx.x >> 6);  // 0..3
    const int k     = blockIdx.x >> 7;         // 128 chunks per head
    const int chunk = blockIdx.x & 127;
    const int lb    = lane & 7;

    // W slice, per-lane XOR-permuted: w[t][j] = Wk[(lane*4+t)*8 + (j^lb)].
    // Loaded vectorized (same traffic as before), permuted once in-register
    // via a 3-layer conditional-swap network (~96 ops, one-time).
    const float* Wk = head_w + (size_t)k * (DD * VV);
    float w[4][8];
    {
        const bool q0 = (lane & 1) != 0;
        const bool q1 = (lane & 2) != 0;
        const bool q2 = (lane & 4) != 0;
#pragma unroll
        for (int t = 0; t < 4; ++t) {
            const float4 a = *(const float4*)(Wk + (lane * 4 + t) * VV);
            const float4 b = *(const float4*)(Wk + (lane * 4 + t) * VV + 4);
            const float x[8] = {a.x, a.y, a.z, a.w, b.x, b.y, b.z, b.w};
            float y[8], z[8];
#pragma unroll
            for (int j = 0; j < 8; ++j) y[j] = q0 ? x[j ^ 1] : x[j];
#pragma unroll
            for (int j = 0; j < 8; ++j) z[j] = q1 ? y[j ^ 2] : y[j];
#pragma unroll
            for (int j = 0; j < 8; ++j) w[t][j] = q2 ? z[j ^ 4] : z[j];
        }
    }
    const float bias = head_b[k * VV + lb];

    const char* fb = (const char*)feats;
    const int s_base = chunk * 128 + wv * 32;          // 32 s per wave
    const int* mi = mask_idx + k * SS + s_base;
    float* outp = out + ((size_t)k * SS + s_base) * VV;
    const int vo = lane << 4;                          // 16B/lane voffset

    int4 rows = *(const int4*)mi;
    int r0 = __builtin_amdgcn_readfirstlane(rows.x);
    int r1 = __builtin_amdgcn_readfirstlane(rows.y);
    int r2 = __builtin_amdgcn_readfirstlane(rows.z);
    int r3 = __builtin_amdgcn_readfirstlane(rows.w);

    for (int i = 0; i < 32; i += 4) {
        // Scalar row bases -> saddr gathers, zero per-gather VALU addr math.
        const float4 f0 = *(const float4*)(fb + (((size_t)(unsigned)r0) << 10) + vo);
        const float4 f1 = *(const float4*)(fb + (((size_t)(unsigned)r1) << 10) + vo);
        const float4 f2 = *(const float4*)(fb + (((size_t)(unsigned)r2) << 10) + vo);
        const float4 f3 = *(const float4*)(fb + (((size_t)(unsigned)r3) << 10) + vo);

        if (i < 28) rows = *(const int4*)(mi + i + 4);   // prefetch next group

        float r[4];
        const float4 f[4] = {f0, f1, f2, f3};
#pragma unroll
        for (int u = 0; u < 4; ++u) {
            float acc[8];
#pragma unroll
            for (int v = 0; v < 8; ++v) {
                acc[v] = f[u].x * w[0][v];
                acc[v] = fmaf(f[u].y, w[1][v], acc[v]);
                acc[v] = fmaf(f[u].z, w[2][v], acc[v]);
                acc[v] = fmaf(f[u].w, w[3][v], acc[v]);
            }
            // v-space split-butterfly, cndmask-free (w pre-permuted):
            // after 3 rounds lane holds partial for v = lane&7 over its
            // 8-lane cluster.
            const float a40 = acc[0] + dpp_mov<0xB1>(acc[1]);
            const float a41 = acc[2] + dpp_mov<0xB1>(acc[3]);
            const float a42 = acc[4] + dpp_mov<0xB1>(acc[5]);
            const float a43 = acc[6] + dpp_mov<0xB1>(acc[7]);
            const float a20 = a40 + dpp_mov<0x4E>(a41);
            const float a21 = a42 + dpp_mov<0x4E>(a43);
            r[u] = a20 + __shfl_xor(a21, 4, 64);
        }

        // refresh scalar bases for next group (stale on last iter, unused)
        r0 = __builtin_amdgcn_readfirstlane(rows.x);
        r1 = __builtin_amdgcn_readfirstlane(rows.y);
        r2 = __builtin_amdgcn_readfirstlane(rows.z);
        r3 = __builtin_amdgcn_readfirstlane(rows.w);

        // s-split tail: xor8 selects s bit0 (lane bit3), xor16 selects s bit1
        // (lane bit4), xor32 plain sum. Lane l<32 ends with
        // out[i + (l>>3)][l&7], lanes 32..63 duplicate.
        const bool b3 = (lane & 8) != 0;
        const bool b4 = (lane & 16) != 0;
        const float t0 = (b3 ? r[1] : r[0]) + dpp_mov<0x128>(b3 ? r[0] : r[1]);
        const float t1 = (b3 ? r[3] : r[2]) + dpp_mov<0x128>(b3 ? r[2] : r[3]);
        float va = (b4 ? t1 : t0) + __shfl_xor(b4 ? t0 : t1, 16, 64);
        va += __shfl_xor(va, 32, 64);

        if (lane < 32) outp[i * VV + lane] = va + bias;
    }
}

extern "C" void kernel_launch(void* const* d_in, const int* in_sizes, int n_in,
                              void* d_out, int out_size, void* d_ws, size_t ws_size,
                              hipStream_t stream) {
    // d_in[0] = block_type_grid (unused by reference)
    const float* feats    = (const float*)d_in[1];
    const int*   mask_idx = (const int*)  d_in[2];
    const float* head_w   = (const float*)d_in[3];
    const float* head_b   = (const float*)d_in[4];
    float* out = (float*)d_out;

    dim3 grid(KH * 128);   // 24 heads * 128 chunks; 128 s per block
    dim3 block(256);
    attr_decoder_kernel<<<grid, block, 0, stream>>>(feats, mask_idx, head_w, head_b, out);
}